// Round 11
// baseline (386.619 us; speedup 1.0000x reference)
//
#include <hip/hip_runtime.h>
#include <hip/hip_bf16.h>
#include <cstdint>
#include <cstddef>

// TeleportationAttention — R22. R21 post-mortem closed the cycle model:
// window time 1237 cyc = 620 MFMA + 576 LDS-read service + barrier, an EXACT
// serial sum — barrier-locked waves on a SIMD all do MFMA together then reads
// together; the pipes never overlap (MfmaUtil 50% ceiling across ALL window
// kernels). R21 put reads first in SOURCE order and got nothing: the reads
// (next k-half, alt frag set) have no dependency on the MFMA cluster, so the
// scheduler is free to sink them below it to save ~24 VGPRs (VGPR 124->128
// corroborates). R22: one-instruction test — __builtin_amdgcn_sched_barrier(0)
// pinned between RD cluster and MFMA cluster in k_gemm2_256 ONLY. Reads must
// then issue first and complete in the LDS pipe (1152 cyc/CU) under the MFMA
// block (1240 cyc/SIMD). Null => hardware port-conflict ceiling; revert to
// R20 4-window gemm2 next round. absmax must stay 0.1289062 exactly.

typedef unsigned short u16;
typedef __attribute__((ext_vector_type(8))) _Float16 half8;
typedef __attribute__((ext_vector_type(4))) float f32x4;

#define B_    4
#define S_    2048
#define D_    512
#define M_TOT (B_ * S_)   // 8192
#define KC    (2 * D_)    // 1024
#define N1    (6 * D_)    // 3072
#define RE_PLANE 4194304  // B*S*D

#define X_ELEMS  ((size_t)M_TOT * KC)
#define W_ELEMS  ((size_t)N1 * KC)
#define QK_ELEMS ((size_t)M_TOT * KC)
#define VT_ELEMS ((size_t)B_ * KC * S_)
#define AT_ELEMS ((size_t)M_TOT * S_)

__device__ __forceinline__ u16 f2h(float f) {
    _Float16 h = (_Float16)f;              // RNE
    return __builtin_bit_cast(u16, h);
}
__device__ __forceinline__ float h2f(u16 b) {
    return (float)__builtin_bit_cast(_Float16, b);
}

__device__ __forceinline__ f32x4 mfma16(half8 a, half8 b, f32x4 c) {
    return __builtin_amdgcn_mfma_f32_16x16x32_f16(a, b, c, 0, 0, 0);
}

// async global->LDS, 16B per lane.
__device__ __forceinline__ void dma16(const u16* g, u16* l) {
    __builtin_amdgcn_global_load_lds(
        (const __attribute__((address_space(1))) unsigned int*)g,
        (__attribute__((address_space(3))) unsigned int*)l,
        16, 0, 0);
}

// ---- 256-row k-half plane (16 KiB, 512 threads), ld = KC ----
__device__ __forceinline__ void stage_half(u16* __restrict__ plane,
                                           const u16* __restrict__ src,
                                           int rowbase, int kcol, int tid) {
#pragma unroll
    for (int i = 0; i < 2; ++i) {
        int c = tid + (i << 9);                 // physical 16B chunk [0,1024)
        int c2 = c ^ (((c >> 5) & 1) << 1);     // logical chunk (involution)
        int row = ((c2 >> 3) << 1) | ((c2 >> 2) & 1);
        int ks = c2 & 3;
        dma16(src + (size_t)(rowbase + row) * KC + (kcol + ks * 8),
              plane + c * 8);
    }
}

// ---- 128-row k-half plane (8 KiB, 256 threads), parametric ld ----
__device__ __forceinline__ void stage_half8(u16* __restrict__ plane,
                                            const u16* __restrict__ src,
                                            int ld, int rowbase, int kcol,
                                            int tid) {
#pragma unroll
    for (int i = 0; i < 2; ++i) {
        int c = tid + (i << 8);                 // physical 16B chunk [0,512)
        int c2 = c ^ (((c >> 5) & 1) << 1);     // logical chunk (involution)
        int row = ((c2 >> 3) << 1) | ((c2 >> 2) & 1);   // [0,128)
        int ks = c2 & 3;
        dma16(src + (size_t)(rowbase + row) * ld + (kcol + ks * 8),
              plane + c * 8);
    }
}

#define VMW(N) asm volatile("s_waitcnt vmcnt(" #N ")" ::: "memory")
#define BAR()  __builtin_amdgcn_s_barrier()
#define SCHB() __builtin_amdgcn_sched_barrier(0)

// ---------------- diagnostic fallback ----------------
__global__ void k_diag(float* __restrict__ out, int out_size, float val) {
    int i = blockIdx.x * 256 + threadIdx.x;
    if (i < out_size && i < 4096) out[i] = val;
}

// ---------------- merged prep: fp32 -> fp16 (X split, W single, bias) ----------------
__global__ void k_prep(const float* __restrict__ xr, const float* __restrict__ xi,
                       const float* __restrict__ Wqr, const float* __restrict__ Wqi,
                       const float* __restrict__ Wkr, const float* __restrict__ Wki,
                       const float* __restrict__ Wvr, const float* __restrict__ Wvi,
                       const float* __restrict__ bqr, const float* __restrict__ bqi,
                       const float* __restrict__ bkr, const float* __restrict__ bki,
                       const float* __restrict__ bvr, const float* __restrict__ bvi,
                       u16* __restrict__ Xh, u16* __restrict__ Xl,
                       u16* __restrict__ Wh, float* __restrict__ bc) {
    int gb = blockIdx.x;
    int tid = threadIdx.x;
    if (gb < 16384) {
        int id = gb * 256 + tid;                 // [0, 4194304)
        int m = id >> 9, d = id & 511;
        size_t o = (size_t)m * KC + d;
        if (o + D_ >= X_ELEMS) return;
        float vr = xr[id], vi = xi[id];
        u16 h;
        h = f2h(vr); Xh[o] = h;        Xl[o] = f2h(vr - h2f(h));
        h = f2h(vi); Xh[o + D_] = h;   Xl[o + D_] = f2h(vi - h2f(h));
    } else if (gb < 16384 + 12288) {
        int id = (gb - 16384) * 256 + tid;       // [0, 3145728)
        int n = id >> 10, k = id & 1023;
        int q = n >> 9, e = n & 511;
        int half = k >> 9, d = k & 511;
        const float* Wre = (q < 2) ? Wqr : ((q < 4) ? Wkr : Wvr);
        const float* Wim = (q < 2) ? Wqi : ((q < 4) ? Wki : Wvi);
        size_t src = (size_t)e * D_ + d;
        float v;
        if ((q & 1) == 0) v = half ? -Wim[src] : Wre[src];
        else              v = half ?  Wre[src] : Wim[src];
        if ((size_t)id < W_ELEMS) Wh[id] = f2h(v);
    } else {
        int id = (gb - 16384 - 12288) * 256 + tid;  // [0, 3072)
        if (id >= N1) return;
        int q = id >> 9, e = id & 511;
        const float* src = (q == 0) ? bqr : (q == 1) ? bqi : (q == 2) ? bkr
                         : (q == 3) ? bki : (q == 4) ? bvr : bvi;
        bc[id] = src[e];
    }
}

// ---------------- shared window machinery (textual macros; use in-scope
// lds/aoffs/boffs/acc; frag stride 512 u16 = 16 rows x 32 k both tiles) ----
#define RDA(d, pl, mg)                                                        \
  { const u16* _pa = &lds[pl][0];                                             \
    _Pragma("unroll")                                                         \
    for (int _i = 0; _i < 4; ++_i)                                            \
      d[_i] = *(const half8*)(_pa + aoffs + ((mg) * 4 + _i) * 512); }
#define RDB(d, pl)                                                            \
  { const u16* _pb = &lds[pl][0];                                             \
    _Pragma("unroll")                                                         \
    for (int _i = 0; _i < 4; ++_i)                                            \
      d[_i] = *(const half8*)(_pb + boffs + _i * 512); }
#define MF16(av, bv, mg)                                                      \
  { __builtin_amdgcn_s_setprio(1);                                            \
    _Pragma("unroll")                                                         \
    for (int _j = 0; _j < 4; ++_j) {                                          \
      _Pragma("unroll")                                                       \
      for (int _i = 0; _i < 4; ++_i)                                          \
        acc[(mg) * 4 + _i][_j] =                                              \
            mfma16(av[_i], bv[_j], acc[(mg) * 4 + _i][_j]);                   \
    }                                                                         \
    __builtin_amdgcn_s_setprio(0); }

#define W0(P, STG, WT) { MF16(aA, bA, 0); RDA(aB, ((P) << 2) | 0, 1); STG; WT; BAR(); }
#define W1(P, STG)     { MF16(aB, bA, 1); RDB(bB, ((P) << 2) | 3); RDA(aA, ((P) << 2) | 1, 0); STG; BAR(); }
#define W2(P, STG, WT) { MF16(aA, bB, 0); RDA(aB, ((P) << 2) | 1, 1); STG; WT; BAR(); }
#define W3(P, STG)     { MF16(aB, bB, 1); RDB(bA, (((P) ^ 1) << 2) | 2); RDA(aA, (((P) ^ 1) << 2) | 0, 0); STG; BAR(); }
#define W3L()          { MF16(aB, bB, 1); }
#define NOP_ ((void)0)

// ---------------- GEMM1-QK (256^2 windows): Q,K projections only ----------------
__global__ __launch_bounds__(512, 2) void k_gemm1qk(
    const u16* __restrict__ Xh, const u16* __restrict__ Xl,
    const u16* __restrict__ Wh,
    const float* __restrict__ bc,
    u16* __restrict__ Qh, u16* __restrict__ Ql,
    u16* __restrict__ Kh, u16* __restrict__ Kl) {
    __shared__ __attribute__((aligned(16))) u16 lds[8][8192];
    int tid = threadIdx.x;
    int L = blockIdx.y * 8 + blockIdx.x;       // linear dispatch index [0,256)
    int xcd = L & 7, slot = L >> 3;            // slot [0,32)
    int by = xcd * 4 + (slot & 3);             // [0,32): 4 m-bands per XCD
    int bx = slot >> 2;                        // [0,8)
    int nb = bx * 256, mb = by * 256;
    int g = bx >> 2;                 // 0:Q 1:K
    const int NT = 32;

    int lane = tid & 63, wave = tid >> 6;
    int wm = (wave >> 2) * 128, wn = (wave & 3) * 64;   // 2x4 waves
    int lr = lane & 15, lq = lane >> 4;
    int lqs8 = (lq ^ (((lr >> 3) & 1) << 1)) * 8;
    int aoffs = (wm + lr) * 32 + lqs8;
    int boffs = (wn + lr) * 32 + lqs8;

    f32x4 acc[8][4] = {};
    half8 aA[4], aB[4], bA[4], bB[4];

    // prologue: tile 0 (both k-halves) + tile 1 k0 => 12 loads in flight
    stage_half(&lds[0][0], Xh, mb, 0, tid);
    stage_half(&lds[2][0], Wh, nb, 0, tid);
    stage_half(&lds[1][0], Xh, mb, 32, tid);
    stage_half(&lds[3][0], Wh, nb, 32, tid);
    stage_half(&lds[4][0], Xh, mb, 64, tid);
    stage_half(&lds[6][0], Wh, nb, 64, tid);
    VMW(8);
    BAR();
    RDB(bA, 2);
    RDA(aA, 0, 0);

    for (int t = 0; t < NT - 2; ++t) {
        const int p = t & 1;
        const u16* s1 = ((t + 1) >= 16) ? Xl : Xh;
        const int k1 = (((t + 1) & 15) << 6) + 32;
        const u16* s2 = ((t + 2) >= 16) ? Xl : Xh;
        const int k2 = ((t + 2) & 15) << 6;
        W0(p, stage_half(&lds[((p ^ 1) << 2) | 1][0], s1, mb, k1, tid), VMW(6));
        W1(p, stage_half(&lds[((p ^ 1) << 2) | 3][0], Wh, nb, k1, tid));
        W2(p, stage_half(&lds[(p << 2) | 0][0], s2, mb, k2, tid), VMW(6));
        W3(p, stage_half(&lds[(p << 2) | 2][0], Wh, nb, k2, tid));
    }
    {   // t = 30 (p = 0): only tile 31's k1 left to stage (seg1: Xl)
        const int k1 = ((31 & 15) << 6) + 32;
        W0(0, stage_half(&lds[(1 << 2) | 1][0], Xl, mb, k1, tid), VMW(6));
        W1(0, stage_half(&lds[(1 << 2) | 3][0], Wh, nb, k1, tid));
        W2(0, NOP_, VMW(4));
        W3(0, NOP_);
    }
    {   // t = 31 (p = 1): drain
        W0(1, NOP_, VMW(0));
        W1(1, NOP_);
        W2(1, NOP_, NOP_);
        W3L();
    }

    // epilogue (Q/K split-fp16 writes; accumulation order unchanged)
#pragma unroll
    for (int j = 0; j < 4; ++j) {
        int n_g = nb + wn + j * 16 + lr;
        float bias = bc[n_g];
        int c = n_g & 1023;
        u16* dh = g ? Kh : Qh;
        u16* dl = g ? Kl : Ql;
#pragma unroll
        for (int i = 0; i < 8; ++i) {
            int m0 = mb + wm + i * 16 + lq * 4;
#pragma unroll
            for (int r = 0; r < 4; ++r) {
                float v = acc[i][j][r] + bias;
                u16 h = f2h(v);
                size_t idx = (size_t)(m0 + r) * KC + c;
                if (idx < QK_ELEMS) {
                    dh[idx] = h;
                    dl[idx] = f2h(v - h2f(h));
                }
            }
        }
    }
}

// ---------------- GEMM1-V (128^2 windows, 2/CU): V projection ----------------
__global__ __launch_bounds__(256, 2) void k_gemm1v(
    const u16* __restrict__ Xh, const u16* __restrict__ Wh,
    const float* __restrict__ bc, u16* __restrict__ VT) {
    __shared__ __attribute__((aligned(16))) u16 lds[8][4096];
    int tid = threadIdx.x;
    int L = blockIdx.y * 8 + blockIdx.x;       // [0,512)
    int xcd = L & 7, slot = L >> 3;            // slot [0,64)
    int by = xcd * 8 + (slot & 7);             // [0,64)
    int bx = slot >> 3;                        // [0,8)
    int nb = 2048 + bx * 128;        // V segment of Wh
    int mb = by * 128;

    int lane = tid & 63, wave = tid >> 6;
    int wm = (wave >> 1) * 64, wn = (wave & 1) * 64;    // 2x2 waves
    int lr = lane & 15, lq = lane >> 4;
    int lqs8 = (lq ^ (((lr >> 3) & 1) << 1)) * 8;
    int aoffs = (wm + lr) * 32 + lqs8;
    int boffs = (wn + lr) * 32 + lqs8;

    f32x4 acc[4][4] = {};
    half8 aA[4], aB[4], bA[4], bB[4];

    // prologue: tile 0 both halves + tile 1 k0
    stage_half8(&lds[0][0], Xh, KC, mb, 0, tid);
    stage_half8(&lds[2][0], Wh, KC, nb, 0, tid);
    stage_half8(&lds[1][0], Xh, KC, mb, 32, tid);
    stage_half8(&lds[3][0], Wh, KC, nb, 32, tid);
    stage_half8(&lds[4][0], Xh, KC, mb, 64, tid);
    stage_half8(&lds[6][0], Wh, KC, nb, 64, tid);
    VMW(4);
    BAR();
    RDA(aA, 0, 0);
    RDB(bA, 2);

    for (int t = 0; t < 14; ++t) {
        const int p = t & 1;
        const int k1 = (t + 1) * 64 + 32;
        const int k2 = (t + 2) * 64;
        MF16(aA, bA, 0);
        RDA(aB, (p << 2) | 1, 0);
        RDB(bB, (p << 2) | 3);
        stage_half8(&lds[((p ^ 1) << 2) | 1][0], Xh, KC, mb, k1, tid);
        stage_half8(&lds[((p ^ 1) << 2) | 3][0], Wh, KC, nb, k1, tid);
        VMW(4);
        BAR();
        MF16(aB, bB, 0);
        RDA(aA, ((p ^ 1) << 2) | 0, 0);
        RDB(bA, ((p ^ 1) << 2) | 2);
        stage_half8(&lds[(p << 2) | 0][0], Xh, KC, mb, k2, tid);
        stage_half8(&lds[(p << 2) | 2][0], Wh, KC, nb, k2, tid);
        VMW(4);
        BAR();
    }
    {   // t = 14 (p = 0): stage tile 15 k1 only
        MF16(aA, bA, 0);
        RDA(aB, 1, 0);
        RDB(bB, 3);
        stage_half8(&lds[(1 << 2) | 1][0], Xh, KC, mb, 15 * 64 + 32, tid);
        stage_half8(&lds[(1 << 2) | 3][0], Wh, KC, nb, 15 * 64 + 32, tid);
        VMW(4);
        BAR();
        MF16(aB, bB, 0);
        RDA(aA, (1 << 2) | 0, 0);
        RDB(bA, (1 << 2) | 2);
        VMW(0);
        BAR();
    }
    {   // t = 15 (p = 1): drain
        MF16(aA, bA, 0);
        RDA(aB, (1 << 2) | 1, 0);
        RDB(bB, (1 << 2) | 3);
        MF16(aB, bB, 0);
    }

    // epilogue: packed VT store (accumulation order unchanged)
#pragma unroll
    for (int j = 0; j < 4; ++j) {
        int n_g = nb + wn + j * 16 + lr;
        float bias = bc[n_g];
        int c = n_g & 1023;
#pragma unroll
        for (int i = 0; i < 4; ++i) {
            int m0 = mb + wm + i * 16 + lq * 4;
            int bidx = m0 >> 11, s0 = m0 & 2047;
            u16 pk[4];
#pragma unroll
            for (int r = 0; r < 4; ++r) pk[r] = f2h(acc[i][j][r] + bias);
            size_t idx = ((size_t)(bidx * KC + c)) * S_ + s0;
            if (idx + 3 < VT_ELEMS)
                *(ushort4*)&VT[idx] = make_ushort4(pk[0], pk[1], pk[2], pk[3]);
        }
    }
}

// ---------------- GEMM2 (256^2, 2-window tiles + sched-pin): ext-K=3072 ----------------
// kh in [0,96): tile t=kh>>1, half h=kh&1; seg = kh>>5: 0 QhKh, 1 QlKh, 2 QhKl.
// Slots: A plane lds[kh&3], B plane lds[4+(kh&3)].
// Window kh: RD regs for kh+1 (alt set); SCHED_BARRIER (pin reads BEFORE
// MFMA — R21 showed source order alone doesn't survive scheduling); MFMA 32
// on kh; stage kh+3; VMW(4); BAR.
#define G2_SRCA(kh) ((((kh) >> 5) == 1) ? Al : Aq)
#define G2_SRCB(kh) ((((kh) >> 5) == 2) ? Bl : Bh)
#define G2_KC(kh)   ((((((kh) >> 1)) & 15) << 6) + (((kh) & 1) << 5))
#define G2_STG(kh)                                                            \
  { stage_half(&lds[(kh) & 3][0], G2_SRCA(kh), mb, G2_KC(kh), tid);           \
    stage_half(&lds[4 + ((kh) & 3)][0], G2_SRCB(kh), nb, G2_KC(kh), tid); }
#define G2_RD(S, kh)                                                          \
  { RDA(a0##S, (kh) & 3, 0); RDA(a1##S, (kh) & 3, 1); RDB(b##S, 4 + ((kh) & 3)); }
#define G2_MF(S) { MF16(a0##S, b##S, 0); MF16(a1##S, b##S, 1); }

__global__ __launch_bounds__(512, 2) void k_gemm2_256(
    const u16* __restrict__ Qh, const u16* __restrict__ Ql,
    const u16* __restrict__ Kh, const u16* __restrict__ Kl,
    float* __restrict__ SC, int zbase) {
    __shared__ __attribute__((aligned(16))) u16 lds[8][8192];
    int tid = threadIdx.x;
    int L = blockIdx.z * 64 + blockIdx.y * 8 + blockIdx.x;  // [0,256)
    int xcd = L & 7, slot = L >> 3;            // slot [0,32)
    int zl = xcd >> 1;                         // local z [0,4)
    int wy = ((xcd & 1) << 2) + (slot & 3);    // [0,8)
    int wx = slot >> 2;                        // [0,8)
    int z = zbase + zl;
    const u16* Aq = Qh + (size_t)z * S_ * KC;
    const u16* Al = Ql + (size_t)z * S_ * KC;
    const u16* Bh = Kh + (size_t)z * S_ * KC;
    const u16* Bl = Kl + (size_t)z * S_ * KC;
    int nb = wx * 256, mb = wy * 256;

    int lane = tid & 63, wave = tid >> 6;
    int wm = (wave >> 2) * 128, wn = (wave & 3) * 64;   // 2x4 waves
    int lr = lane & 15, lq = lane >> 4;
    int lqs8 = (lq ^ (((lr >> 3) & 1) << 1)) * 8;
    int aoffs = (wm + lr) * 32 + lqs8;
    int boffs = (wn + lr) * 32 + lqs8;

    f32x4 acc[8][4] = {};
    half8 a0X[4], a1X[4], bX[4];    // frag set X
    half8 a0Y[4], a1Y[4], bY[4];    // frag set Y

    // prologue: stage kh0,kh1,kh2 (12 loads); kh0+kh1 landed; read kh0 -> Y
    G2_STG(0);
    G2_STG(1);
    G2_STG(2);
    VMW(4);
    BAR();
    G2_RD(Y, 0);

    // steady state: windows 0..91 (even: RD X / MF Y; odd: RD Y / MF X)
    for (int w = 0; w < 92; w += 2) {
        G2_RD(X, w + 1); SCHB(); G2_MF(Y); G2_STG(w + 3); VMW(4); BAR();
        G2_RD(Y, w + 2); SCHB(); G2_MF(X); G2_STG(w + 4); VMW(4); BAR();
    }
    // window 92: last stage (kh95)
    G2_RD(X, 93); SCHB(); G2_MF(Y); G2_STG(95); VMW(4); BAR();
    // window 93: drain remaining loads (kh95)
    G2_RD(Y, 94); SCHB(); G2_MF(X); VMW(0); BAR();
    // window 94
    G2_RD(X, 95); SCHB(); G2_MF(Y);
    // window 95
    G2_MF(X);

    // epilogue: SC[zl][m][n] fp32
    size_t sc_limit = (size_t)gridDim.z * S_ * S_;
#pragma unroll
    for (int j = 0; j < 4; ++j) {
        int n_g = nb + wn + j * 16 + lr;
#pragma unroll
        for (int i = 0; i < 8; ++i) {
            int m0 = mb + wm + i * 16 + lq * 4;
#pragma unroll
            for (int r = 0; r < 4; ++r) {
                size_t idx = ((size_t)zl * S_ + m0 + r) * S_ + n_g;
                if (idx < sc_limit) SC[idx] = acc[i][j][r];
            }
        }
    }
}

// ---------------- GEMM2 (128^2 windows, zc<4 fallback): extended-K=3072 ----------------
__global__ __launch_bounds__(256, 2) void k_gemm2w(
    const u16* __restrict__ Qh, const u16* __restrict__ Ql,
    const u16* __restrict__ Kh, const u16* __restrict__ Kl,
    float* __restrict__ SC, int zbase) {
    __shared__ __attribute__((aligned(16))) u16 lds[8][4096];
    int tid = threadIdx.x;
    int z = zbase + blockIdx.z;
    const u16* Aq  = Qh + (size_t)z * S_ * KC;
    const u16* Alo = Ql + (size_t)z * S_ * KC;
    const u16* Bh  = Kh + (size_t)z * S_ * KC;
    const u16* Blo = Kl + (size_t)z * S_ * KC;
    int nb = blockIdx.x * 128, mb = blockIdx.y * 128;

    int lane = tid & 63, wave = tid >> 6;
    int wm = (wave >> 1) * 64, wn = (wave & 1) * 64;    // 2x2 waves
    int lr = lane & 15, lq = lane >> 4;
    int lqs8 = (lq ^ (((lr >> 3) & 1) << 1)) * 8;
    int aoffs = (wm + lr) * 32 + lqs8;
    int boffs = (wn + lr) * 32 + lqs8;

    f32x4 acc[4][4] = {};
    half8 aA[4], aB[4], bA[4], bB[4];

    stage_half8(&lds[0][0], Aq, KC, mb, 0, tid);
    stage_half8(&lds[2][0], Bh, KC, nb, 0, tid);
    stage_half8(&lds[1][0], Aq, KC, mb, 32, tid);
    stage_half8(&lds[3][0], Bh, KC, nb, 32, tid);
    stage_half8(&lds[4][0], Aq, KC, mb, 64, tid);
    stage_half8(&lds[6][0], Bh, KC, nb, 64, tid);
    VMW(4);
    BAR();
    RDA(aA, 0, 0);
    RDB(bA, 2);

    for (int t = 0; t < 46; ++t) {
        const int p = t & 1;
        const int t1 = t + 1, t2 = t + 2;
        const u16* a1 = ((t1 >> 4) == 1) ? Alo : Aq;
        const u16* b1 = ((t1 >> 4) == 2) ? Blo : Bh;
        const u16* a2 = ((t2 >> 4) == 1) ? Alo : Aq;
        const u16* b2 = ((t2 >> 4) == 2) ? Blo : Bh;
        const int k1 = ((t1 & 15) << 6) + 32;
        const int k2 = (t2 & 15) << 6;
        MF16(aA, bA, 0);
        RDA(aB, (p << 2) | 1, 0);
        RDB(bB, (p << 2) | 3);
        stage_half8(&lds[((p ^ 1) << 2) | 1][0], a1, KC, mb, k1, tid);
        stage_half8(&lds[((p ^ 1) << 2) | 3][0], b1, KC, nb, k1, tid);
        VMW(4);
        BAR();
        MF16(aB, bB, 0);
        RDA(aA, ((p ^ 1) << 2) | 0, 0);
        RDB(bA, ((p ^ 1) << 2) | 2);
        stage_half8(&lds[(p << 2) | 0][0], a2, KC, mb, k2, tid);
        stage_half8(&lds[(p << 2) | 2][0], b2, KC, nb, k2, tid);
        VMW(4);
        BAR();
    }
    {   // t = 46 (p = 0)
        MF16(aA, bA, 0);
        RDA(aB, 1, 0);
        RDB(bB, 3);
        stage_half8(&lds[(1 << 2) | 1][0], Aq, KC, mb, ((47 & 15) << 6) + 32, tid);
        stage_half8(&lds[(1 << 2) | 3][0], Blo, KC, nb, ((47 & 15) << 6) + 32, tid);
        VMW(4);
        BAR();
        MF16(aB, bB, 0);
        RDA(aA, (1 << 2) | 0, 0);
        RDB(bA, (1 << 2) | 2);
        VMW(0);
        BAR();
    }
    {   // t = 47 (p = 1): drain
        MF16(aA, bA, 0);
        RDA(aB, (1 << 2) | 1, 0);
        RDB(bB, (1 << 2) | 3);
        MF16(aB, bB, 0);
    }

    size_t sc_limit = (size_t)gridDim.z * S_ * S_;
#pragma unroll
    for (int j = 0; j < 4; ++j) {
        int n_g = nb + wn + j * 16 + lr;
#pragma unroll
        for (int i = 0; i < 4; ++i) {
            int m0 = mb + wm + i * 16 + lq * 4;
#pragma unroll
            for (int r = 0; r < 4; ++r) {
                size_t idx = ((size_t)blockIdx.z * S_ + m0 + r) * S_ + n_g;
                if (idx < sc_limit) SC[idx] = acc[i][j][r];
            }
        }
    }
}

// ---------------- softmax: SC fp32 -> AT fp16 (vectorized I/O) ----------------
__global__ __launch_bounds__(256) void k_softmax(const float* __restrict__ SC,
                                                 u16* __restrict__ AT, int zbase) {
    int row = blockIdx.x;
    const float* src = SC + (size_t)row * S_;
    size_t drow = (size_t)zbase * S_ + row;
    u16* dst = AT + drow * S_;
    int tid = threadIdx.x;
    float4 va = *(const float4*)(src + tid * 8);
    float4 vb = *(const float4*)(src + tid * 8 + 4);
    float v[8] = {va.x, va.y, va.z, va.w, vb.x, vb.y, vb.z, vb.w};
    float m = v[0];
#pragma unroll
    for (int i = 1; i < 8; ++i) m = fmaxf(m, v[i]);
    for (int off = 32; off > 0; off >>= 1) m = fmaxf(m, __shfl_down(m, off));
    __shared__ float redm[4], reds[4];
    if ((tid & 63) == 0) redm[tid >> 6] = m;
    __syncthreads();
    m = fmaxf(fmaxf(redm[0], redm[1]), fmaxf(redm[2], redm[3]));
    float s = 0.f;
#pragma unroll
    for (int i = 0; i < 8; ++i) { v[i] = __expf(v[i] - m); s += v[i]; }
    for (int off = 32; off > 0; off >>= 1) s += __shfl_down(s, off);
    if ((tid & 63) == 0) reds[tid >> 6] = s;
    __syncthreads();
    float inv = 1.0f / (reds[0] + reds[1] + reds[2] + reds[3]);
    if (drow * S_ + 2047 < AT_ELEMS) {
        u16 pk[8];
#pragma unroll
        for (int i = 0; i < 8; ++i) pk[i] = f2h(v[i] * inv);
        uint4 o;
        o.x = (unsigned)pk[0] | ((unsigned)pk[1] << 16);
        o.y = (unsigned)pk[2] | ((unsigned)pk[3] << 16);
        o.z = (unsigned)pk[4] | ((unsigned)pk[5] << 16);
        o.w = (unsigned)pk[6] | ((unsigned)pk[7] << 16);
        *(uint4*)(dst + tid * 8) = o;
    }
}

// ---------------- GEMM3 (128^2 windows): out = attn @ Vcat, NT=32 ----------------
__global__ __launch_bounds__(256, 2) void k_gemm3w(
    const u16* __restrict__ AT, const u16* __restrict__ VT,
    float* __restrict__ out, int out_size, int full) {
    __shared__ __attribute__((aligned(16))) u16 lds[8][4096];
    int tid = threadIdx.x;
    int L = blockIdx.z * 128 + blockIdx.y * 8 + blockIdx.x;  // [0,512)
    int xcd = L & 7, slot = L >> 3;            // slot [0,64)
    int z = xcd >> 1;                          // [0,4)
    int wy = ((xcd & 1) << 3) + (slot & 7);    // [0,16)
    int wx = slot >> 3;                        // [0,8)
    const u16* Abase = AT + (size_t)z * S_ * S_;   // [S][S], ld=S
    const u16* Bbase = VT + (size_t)z * KC * S_;   // [KC][S], ld=S (B^T form)
    int nb = wx * 128, mb = wy * 128;

    int lane = tid & 63, wave = tid >> 6;
    int wm = (wave >> 1) * 64, wn = (wave & 1) * 64;    // 2x2 waves
    int lr = lane & 15, lq = lane >> 4;
    int lqs8 = (lq ^ (((lr >> 3) & 1) << 1)) * 8;
    int aoffs = (wm + lr) * 32 + lqs8;
    int boffs = (wn + lr) * 32 + lqs8;

    f32x4 acc[4][4] = {};
    half8 aA[4], aB[4], bA[4], bB[4];

    // prologue: tile 0 both halves + tile 1 k0
    stage_half8(&lds[0][0], Abase, S_, mb, 0, tid);
    stage_half8(&lds[2][0], Bbase, S_, nb, 0, tid);
    stage_half8(&lds[1][0], Abase, S_, mb, 32, tid);
    stage_half8(&lds[3][0], Bbase, S_, nb, 32, tid);
    stage_half8(&lds[4][0], Abase, S_, mb, 64, tid);
    stage_half8(&lds[6][0], Bbase, S_, nb, 64, tid);
    VMW(4);
    BAR();
    RDA(aA, 0, 0);
    RDB(bA, 2);

    for (int t = 0; t < 30; ++t) {
        const int p = t & 1;
        const int k1 = (t + 1) * 64 + 32;
        const int k2 = (t + 2) * 64;
        MF16(aA, bA, 0);
        RDA(aB, (p << 2) | 1, 0);
        RDB(bB, (p << 2) | 3);
        stage_half8(&lds[((p ^ 1) << 2) | 1][0], Abase, S_, mb, k1, tid);
        stage_half8(&lds[((p ^ 1) << 2) | 3][0], Bbase, S_, nb, k1, tid);
        VMW(4);
        BAR();
        MF16(aB, bB, 0);
        RDA(aA, ((p ^ 1) << 2) | 0, 0);
        RDB(bA, ((p ^ 1) << 2) | 2);
        stage_half8(&lds[(p << 2) | 0][0], Abase, S_, mb, k2, tid);
        stage_half8(&lds[(p << 2) | 2][0], Bbase, S_, nb, k2, tid);
        VMW(4);
        BAR();
    }
    {   // t = 30 (p = 0): stage tile 31 k1 only
        MF16(aA, bA, 0);
        RDA(aB, 1, 0);
        RDB(bB, 3);
        stage_half8(&lds[(1 << 2) | 1][0], Abase, S_, mb, 31 * 64 + 32, tid);
        stage_half8(&lds[(1 << 2) | 3][0], Bbase, S_, nb, 31 * 64 + 32, tid);
        VMW(4);
        BAR();
        MF16(aB, bB, 0);
        RDA(aA, (1 << 2) | 0, 0);
        RDB(bA, (1 << 2) | 2);
        VMW(0);
        BAR();
    }
    {   // t = 31 (p = 1): drain
        MF16(aA, bA, 0);
        RDA(aB, (1 << 2) | 1, 0);
        RDB(bB, (1 << 2) | 3);
        MF16(aB, bB, 0);
    }

    // planar epilogue
#pragma unroll
    for (int j = 0; j < 4; ++j) {
        int f = nb + wn + j * 16 + lr;
#pragma unroll
        for (int i = 0; i < 4; ++i) {
            int s0 = mb + wm + i * 16 + lq * 4;
#pragma unroll
            for (int r = 0; r < 4; ++r) {
                size_t base = ((size_t)z * S_ + s0 + r) * D_;
                if (f < D_) {
                    size_t o = base + f;
                    if (o < (size_t)out_size) out[o] = acc[i][j][r];
                } else if (full) {
                    size_t o = (size_t)RE_PLANE + base + (f - D_);
                    if (o < (size_t)out_size) out[o] = acc[i][j][r];
                }
            }
        }
    }
}

// ---------------- launch ----------------

extern "C" void kernel_launch(void* const* d_in, const int* in_sizes, int n_in,
                              void* d_out, int out_size, void* d_ws, size_t ws_size,
                              hipStream_t stream) {
    (void)in_sizes; (void)n_in;
    const float* xr  = (const float*)d_in[0];
    const float* xi  = (const float*)d_in[1];
    const float* Wqr = (const float*)d_in[2];
    const float* Wqi = (const float*)d_in[3];
    const float* bqr = (const float*)d_in[4];
    const float* bqi = (const float*)d_in[5];
    const float* Wkr = (const float*)d_in[6];
    const float* Wki = (const float*)d_in[7];
    const float* bkr = (const float*)d_in[8];
    const float* bki = (const float*)d_in[9];
    const float* Wvr = (const float*)d_in[10];
    const float* Wvi = (const float*)d_in[11];
    const float* bvr = (const float*)d_in[12];
    const float* bvi = (const float*)d_in[13];
    float* out = (float*)d_out;

    constexpr size_t SZ_X  = X_ELEMS * 2;          // 16 MiB each (Xh, Xl)
    constexpr size_t SZ_W  = W_ELEMS * 2;          // 6 MiB
    constexpr size_t SZ_BC = (size_t)N1 * 4;
    constexpr size_t SZ_QK = QK_ELEMS * 2;         // 16 MiB each (Qh,Ql,Kh,Kl)
    constexpr size_t SZ_VT = VT_ELEMS * 2;         // 16 MiB
    constexpr size_t SZ_SC_B = (size_t)S_ * S_ * 4;  // 16 MiB per batch

    char* p = (char*)d_ws;
    size_t off = 0;
    auto take = [&](size_t sz) {
        char* r = p + off;
        off += (sz + 255) & ~(size_t)255;
        return r;
    };
    u16*   Xh = (u16*)take(SZ_X);
    u16*   Xl = (u16*)take(SZ_X);
    u16*   Wh = (u16*)take(SZ_W);
    float* bc = (float*)take(SZ_BC);
    u16*   Qh = (u16*)take(SZ_QK);
    u16*   Ql = (u16*)take(SZ_QK);
    u16*   Kh = (u16*)take(SZ_QK);
    u16*   Kl = (u16*)take(SZ_QK);
    u16*   VT = (u16*)take(SZ_VT);
    u16*   AT = Xh;  // aliases Xh+Xl (32 MiB, dead after gemm1 kernels)
    float* SC = (float*)(p + off);

    int nz = 0;
    if (ws_size > off) nz = (int)((ws_size - off) / SZ_SC_B);
    if (nz > B_) nz = B_;
    if (nz < 1) {
        k_diag<<<16, 256, 0, stream>>>(out, out_size, 1000.0f + (float)(ws_size >> 20));
        return;
    }

    int full = (out_size >= 2 * RE_PLANE) ? 1 : 0;

    k_prep<<<16384 + 12288 + 12, 256, 0, stream>>>(
        xr, xi, Wqr, Wqi, Wkr, Wki, Wvr, Wvi,
        bqr, bqi, bkr, bki, bvr, bvi, Xh, Xl, Wh, bc);
    k_gemm1qk<<<dim3(8, 32), 512, 0, stream>>>(Xh, Xl, Wh, bc, Qh, Ql, Kh, Kl);
    k_gemm1v<<<dim3(8, 64), 256, 0, stream>>>(Xh, Wh, bc, VT);

    for (int z0 = 0; z0 < B_; z0 += nz) {
        int zc = (B_ - z0 < nz) ? (B_ - z0) : nz;
        if (zc == B_) {
            k_gemm2_256<<<dim3(8, 8, 4), 512, 0, stream>>>(
                Qh, Ql, Kh, Kl, SC, z0);
        } else {
            k_gemm2w<<<dim3(S_ / 128, S_ / 128, zc), 256, 0, stream>>>(
                Qh, Ql, Kh, Kl, SC, z0);
        }
        k_softmax<<<zc * S_, 256, 0, stream>>>(SC, AT, z0);
    }
    k_gemm3w<<<dim3(KC / 128, S_ / 128, B_), 256, 0, stream>>>(AT, VT, out, out_size, full);
}

// Round 12
// 366.402 us; speedup vs baseline: 1.0552x; 1.0552x over previous
//
#include <hip/hip_runtime.h>
#include <hip/hip_bf16.h>
#include <cstdint>
#include <cstddef>

// TeleportationAttention — R23. R21 (reads-first) and R22 (sched_barrier pin)
// both null: the window template's MFMA/LDS serialization is its ceiling on
// this HW (MfmaUtil ~46-50% plateau; matches the guide's m97-structure
// phenomenon where source-level scheduling doesn't move the needle).
// Executing the R22 pre-commitment:
//  (1) k_gemm2_256 reverted to R20's 4-window version (measured 98.7-99.9us
//      vs R21/R22's 103.6-105.6) — keeps z-patch XCD swizzle (FETCH 74MB).
//  (2) k_prep X-branch vectorized (G13): float4 loads + ushort4 stores,
//      4 elem/thread; values bit-identical -> absmax must stay 0.1289062.
// All else identical to R20/R22 common state.

typedef unsigned short u16;
typedef __attribute__((ext_vector_type(8))) _Float16 half8;
typedef __attribute__((ext_vector_type(4))) float f32x4;

#define B_    4
#define S_    2048
#define D_    512
#define M_TOT (B_ * S_)   // 8192
#define KC    (2 * D_)    // 1024
#define N1    (6 * D_)    // 3072
#define RE_PLANE 4194304  // B*S*D

#define X_ELEMS  ((size_t)M_TOT * KC)
#define W_ELEMS  ((size_t)N1 * KC)
#define QK_ELEMS ((size_t)M_TOT * KC)
#define VT_ELEMS ((size_t)B_ * KC * S_)
#define AT_ELEMS ((size_t)M_TOT * S_)

__device__ __forceinline__ u16 f2h(float f) {
    _Float16 h = (_Float16)f;              // RNE
    return __builtin_bit_cast(u16, h);
}
__device__ __forceinline__ float h2f(u16 b) {
    return (float)__builtin_bit_cast(_Float16, b);
}

__device__ __forceinline__ f32x4 mfma16(half8 a, half8 b, f32x4 c) {
    return __builtin_amdgcn_mfma_f32_16x16x32_f16(a, b, c, 0, 0, 0);
}

// async global->LDS, 16B per lane.
__device__ __forceinline__ void dma16(const u16* g, u16* l) {
    __builtin_amdgcn_global_load_lds(
        (const __attribute__((address_space(1))) unsigned int*)g,
        (__attribute__((address_space(3))) unsigned int*)l,
        16, 0, 0);
}

// ---- 256-row k-half plane (16 KiB, 512 threads), ld = KC ----
__device__ __forceinline__ void stage_half(u16* __restrict__ plane,
                                           const u16* __restrict__ src,
                                           int rowbase, int kcol, int tid) {
#pragma unroll
    for (int i = 0; i < 2; ++i) {
        int c = tid + (i << 9);                 // physical 16B chunk [0,1024)
        int c2 = c ^ (((c >> 5) & 1) << 1);     // logical chunk (involution)
        int row = ((c2 >> 3) << 1) | ((c2 >> 2) & 1);
        int ks = c2 & 3;
        dma16(src + (size_t)(rowbase + row) * KC + (kcol + ks * 8),
              plane + c * 8);
    }
}

// ---- 128-row k-half plane (8 KiB, 256 threads), parametric ld ----
__device__ __forceinline__ void stage_half8(u16* __restrict__ plane,
                                            const u16* __restrict__ src,
                                            int ld, int rowbase, int kcol,
                                            int tid) {
#pragma unroll
    for (int i = 0; i < 2; ++i) {
        int c = tid + (i << 8);                 // physical 16B chunk [0,512)
        int c2 = c ^ (((c >> 5) & 1) << 1);     // logical chunk (involution)
        int row = ((c2 >> 3) << 1) | ((c2 >> 2) & 1);   // [0,128)
        int ks = c2 & 3;
        dma16(src + (size_t)(rowbase + row) * ld + (kcol + ks * 8),
              plane + c * 8);
    }
}

#define VMW(N) asm volatile("s_waitcnt vmcnt(" #N ")" ::: "memory")
#define BAR()  __builtin_amdgcn_s_barrier()

// ---------------- diagnostic fallback ----------------
__global__ void k_diag(float* __restrict__ out, int out_size, float val) {
    int i = blockIdx.x * 256 + threadIdx.x;
    if (i < out_size && i < 4096) out[i] = val;
}

// ---------------- merged prep: fp32 -> fp16 (X split vectorized, W, bias) ----------------
__global__ void k_prep(const float* __restrict__ xr, const float* __restrict__ xi,
                       const float* __restrict__ Wqr, const float* __restrict__ Wqi,
                       const float* __restrict__ Wkr, const float* __restrict__ Wki,
                       const float* __restrict__ Wvr, const float* __restrict__ Wvi,
                       const float* __restrict__ bqr, const float* __restrict__ bqi,
                       const float* __restrict__ bkr, const float* __restrict__ bki,
                       const float* __restrict__ bvr, const float* __restrict__ bvi,
                       u16* __restrict__ Xh, u16* __restrict__ Xl,
                       u16* __restrict__ Wh, float* __restrict__ bc) {
    int gb = blockIdx.x;
    int tid = threadIdx.x;
    if (gb < 4096) {
        int id = (gb * 256 + tid) * 4;           // [0, 4194304), 4-aligned
        int m = id >> 9, d = id & 511;           // d..d+3 within one 512-half
        size_t o = (size_t)m * KC + d;
        if (o + D_ + 3 >= X_ELEMS) return;
        float4 vr = *(const float4*)(xr + id);
        float4 vi = *(const float4*)(xi + id);
        ushort4 hr, er, hi4, ei;
        u16 h;
        h = f2h(vr.x); hr.x = h; er.x = f2h(vr.x - h2f(h));
        h = f2h(vr.y); hr.y = h; er.y = f2h(vr.y - h2f(h));
        h = f2h(vr.z); hr.z = h; er.z = f2h(vr.z - h2f(h));
        h = f2h(vr.w); hr.w = h; er.w = f2h(vr.w - h2f(h));
        h = f2h(vi.x); hi4.x = h; ei.x = f2h(vi.x - h2f(h));
        h = f2h(vi.y); hi4.y = h; ei.y = f2h(vi.y - h2f(h));
        h = f2h(vi.z); hi4.z = h; ei.z = f2h(vi.z - h2f(h));
        h = f2h(vi.w); hi4.w = h; ei.w = f2h(vi.w - h2f(h));
        *(ushort4*)&Xh[o] = hr;        *(ushort4*)&Xl[o] = er;
        *(ushort4*)&Xh[o + D_] = hi4;  *(ushort4*)&Xl[o + D_] = ei;
    } else if (gb < 4096 + 12288) {
        int id = (gb - 4096) * 256 + tid;        // [0, 3145728)
        int n = id >> 10, k = id & 1023;
        int q = n >> 9, e = n & 511;
        int half = k >> 9, d = k & 511;
        const float* Wre = (q < 2) ? Wqr : ((q < 4) ? Wkr : Wvr);
        const float* Wim = (q < 2) ? Wqi : ((q < 4) ? Wki : Wvi);
        size_t src = (size_t)e * D_ + d;
        float v;
        if ((q & 1) == 0) v = half ? -Wim[src] : Wre[src];
        else              v = half ?  Wre[src] : Wim[src];
        if ((size_t)id < W_ELEMS) Wh[id] = f2h(v);
    } else {
        int id = (gb - 4096 - 12288) * 256 + tid;  // [0, 3072)
        if (id >= N1) return;
        int q = id >> 9, e = id & 511;
        const float* src = (q == 0) ? bqr : (q == 1) ? bqi : (q == 2) ? bkr
                         : (q == 3) ? bki : (q == 4) ? bvr : bvi;
        bc[id] = src[e];
    }
}

// ---------------- shared window machinery (textual macros; use in-scope
// lds/aoffs/boffs/acc; frag stride 512 u16 = 16 rows x 32 k both tiles) ----
#define RDA(d, pl, mg)                                                        \
  { const u16* _pa = &lds[pl][0];                                             \
    _Pragma("unroll")                                                         \
    for (int _i = 0; _i < 4; ++_i)                                            \
      d[_i] = *(const half8*)(_pa + aoffs + ((mg) * 4 + _i) * 512); }
#define RDB(d, pl)                                                            \
  { const u16* _pb = &lds[pl][0];                                             \
    _Pragma("unroll")                                                         \
    for (int _i = 0; _i < 4; ++_i)                                            \
      d[_i] = *(const half8*)(_pb + boffs + _i * 512); }
#define MF16(av, bv, mg)                                                      \
  { __builtin_amdgcn_s_setprio(1);                                            \
    _Pragma("unroll")                                                         \
    for (int _j = 0; _j < 4; ++_j) {                                          \
      _Pragma("unroll")                                                       \
      for (int _i = 0; _i < 4; ++_i)                                          \
        acc[(mg) * 4 + _i][_j] =                                              \
            mfma16(av[_i], bv[_j], acc[(mg) * 4 + _i][_j]);                   \
    }                                                                         \
    __builtin_amdgcn_s_setprio(0); }

#define W0(P, STG, WT) { MF16(aA, bA, 0); RDA(aB, ((P) << 2) | 0, 1); STG; WT; BAR(); }
#define W1(P, STG)     { MF16(aB, bA, 1); RDB(bB, ((P) << 2) | 3); RDA(aA, ((P) << 2) | 1, 0); STG; BAR(); }
#define W2(P, STG, WT) { MF16(aA, bB, 0); RDA(aB, ((P) << 2) | 1, 1); STG; WT; BAR(); }
#define W3(P, STG)     { MF16(aB, bB, 1); RDB(bA, (((P) ^ 1) << 2) | 2); RDA(aA, (((P) ^ 1) << 2) | 0, 0); STG; BAR(); }
#define W3L()          { MF16(aB, bB, 1); }
#define NOP_ ((void)0)

// ---------------- GEMM1-QK (256^2 windows): Q,K projections only ----------------
__global__ __launch_bounds__(512, 2) void k_gemm1qk(
    const u16* __restrict__ Xh, const u16* __restrict__ Xl,
    const u16* __restrict__ Wh,
    const float* __restrict__ bc,
    u16* __restrict__ Qh, u16* __restrict__ Ql,
    u16* __restrict__ Kh, u16* __restrict__ Kl) {
    __shared__ __attribute__((aligned(16))) u16 lds[8][8192];
    int tid = threadIdx.x;
    int L = blockIdx.y * 8 + blockIdx.x;       // linear dispatch index [0,256)
    int xcd = L & 7, slot = L >> 3;            // slot [0,32)
    int by = xcd * 4 + (slot & 3);             // [0,32): 4 m-bands per XCD
    int bx = slot >> 2;                        // [0,8)
    int nb = bx * 256, mb = by * 256;
    int g = bx >> 2;                 // 0:Q 1:K
    const int NT = 32;

    int lane = tid & 63, wave = tid >> 6;
    int wm = (wave >> 2) * 128, wn = (wave & 3) * 64;   // 2x4 waves
    int lr = lane & 15, lq = lane >> 4;
    int lqs8 = (lq ^ (((lr >> 3) & 1) << 1)) * 8;
    int aoffs = (wm + lr) * 32 + lqs8;
    int boffs = (wn + lr) * 32 + lqs8;

    f32x4 acc[8][4] = {};
    half8 aA[4], aB[4], bA[4], bB[4];

    // prologue: tile 0 (both k-halves) + tile 1 k0 => 12 loads in flight
    stage_half(&lds[0][0], Xh, mb, 0, tid);
    stage_half(&lds[2][0], Wh, nb, 0, tid);
    stage_half(&lds[1][0], Xh, mb, 32, tid);
    stage_half(&lds[3][0], Wh, nb, 32, tid);
    stage_half(&lds[4][0], Xh, mb, 64, tid);
    stage_half(&lds[6][0], Wh, nb, 64, tid);
    VMW(8);
    BAR();
    RDB(bA, 2);
    RDA(aA, 0, 0);

    for (int t = 0; t < NT - 2; ++t) {
        const int p = t & 1;
        const u16* s1 = ((t + 1) >= 16) ? Xl : Xh;
        const int k1 = (((t + 1) & 15) << 6) + 32;
        const u16* s2 = ((t + 2) >= 16) ? Xl : Xh;
        const int k2 = ((t + 2) & 15) << 6;
        W0(p, stage_half(&lds[((p ^ 1) << 2) | 1][0], s1, mb, k1, tid), VMW(6));
        W1(p, stage_half(&lds[((p ^ 1) << 2) | 3][0], Wh, nb, k1, tid));
        W2(p, stage_half(&lds[(p << 2) | 0][0], s2, mb, k2, tid), VMW(6));
        W3(p, stage_half(&lds[(p << 2) | 2][0], Wh, nb, k2, tid));
    }
    {   // t = 30 (p = 0): only tile 31's k1 left to stage (seg1: Xl)
        const int k1 = ((31 & 15) << 6) + 32;
        W0(0, stage_half(&lds[(1 << 2) | 1][0], Xl, mb, k1, tid), VMW(6));
        W1(0, stage_half(&lds[(1 << 2) | 3][0], Wh, nb, k1, tid));
        W2(0, NOP_, VMW(4));
        W3(0, NOP_);
    }
    {   // t = 31 (p = 1): drain
        W0(1, NOP_, VMW(0));
        W1(1, NOP_);
        W2(1, NOP_, NOP_);
        W3L();
    }

    // epilogue (Q/K split-fp16 writes; accumulation order unchanged)
#pragma unroll
    for (int j = 0; j < 4; ++j) {
        int n_g = nb + wn + j * 16 + lr;
        float bias = bc[n_g];
        int c = n_g & 1023;
        u16* dh = g ? Kh : Qh;
        u16* dl = g ? Kl : Ql;
#pragma unroll
        for (int i = 0; i < 8; ++i) {
            int m0 = mb + wm + i * 16 + lq * 4;
#pragma unroll
            for (int r = 0; r < 4; ++r) {
                float v = acc[i][j][r] + bias;
                u16 h = f2h(v);
                size_t idx = (size_t)(m0 + r) * KC + c;
                if (idx < QK_ELEMS) {
                    dh[idx] = h;
                    dl[idx] = f2h(v - h2f(h));
                }
            }
        }
    }
}

// ---------------- GEMM1-V (128^2 windows, 2/CU): V projection ----------------
__global__ __launch_bounds__(256, 2) void k_gemm1v(
    const u16* __restrict__ Xh, const u16* __restrict__ Wh,
    const float* __restrict__ bc, u16* __restrict__ VT) {
    __shared__ __attribute__((aligned(16))) u16 lds[8][4096];
    int tid = threadIdx.x;
    int L = blockIdx.y * 8 + blockIdx.x;       // [0,512)
    int xcd = L & 7, slot = L >> 3;            // slot [0,64)
    int by = xcd * 8 + (slot & 7);             // [0,64)
    int bx = slot >> 3;                        // [0,8)
    int nb = 2048 + bx * 128;        // V segment of Wh
    int mb = by * 128;

    int lane = tid & 63, wave = tid >> 6;
    int wm = (wave >> 1) * 64, wn = (wave & 1) * 64;    // 2x2 waves
    int lr = lane & 15, lq = lane >> 4;
    int lqs8 = (lq ^ (((lr >> 3) & 1) << 1)) * 8;
    int aoffs = (wm + lr) * 32 + lqs8;
    int boffs = (wn + lr) * 32 + lqs8;

    f32x4 acc[4][4] = {};
    half8 aA[4], aB[4], bA[4], bB[4];

    // prologue: tile 0 both halves + tile 1 k0
    stage_half8(&lds[0][0], Xh, KC, mb, 0, tid);
    stage_half8(&lds[2][0], Wh, KC, nb, 0, tid);
    stage_half8(&lds[1][0], Xh, KC, mb, 32, tid);
    stage_half8(&lds[3][0], Wh, KC, nb, 32, tid);
    stage_half8(&lds[4][0], Xh, KC, mb, 64, tid);
    stage_half8(&lds[6][0], Wh, KC, nb, 64, tid);
    VMW(4);
    BAR();
    RDA(aA, 0, 0);
    RDB(bA, 2);

    for (int t = 0; t < 14; ++t) {
        const int p = t & 1;
        const int k1 = (t + 1) * 64 + 32;
        const int k2 = (t + 2) * 64;
        MF16(aA, bA, 0);
        RDA(aB, (p << 2) | 1, 0);
        RDB(bB, (p << 2) | 3);
        stage_half8(&lds[((p ^ 1) << 2) | 1][0], Xh, KC, mb, k1, tid);
        stage_half8(&lds[((p ^ 1) << 2) | 3][0], Wh, KC, nb, k1, tid);
        VMW(4);
        BAR();
        MF16(aB, bB, 0);
        RDA(aA, ((p ^ 1) << 2) | 0, 0);
        RDB(bA, ((p ^ 1) << 2) | 2);
        stage_half8(&lds[(p << 2) | 0][0], Xh, KC, mb, k2, tid);
        stage_half8(&lds[(p << 2) | 2][0], Wh, KC, nb, k2, tid);
        VMW(4);
        BAR();
    }
    {   // t = 14 (p = 0): stage tile 15 k1 only
        MF16(aA, bA, 0);
        RDA(aB, 1, 0);
        RDB(bB, 3);
        stage_half8(&lds[(1 << 2) | 1][0], Xh, KC, mb, 15 * 64 + 32, tid);
        stage_half8(&lds[(1 << 2) | 3][0], Wh, KC, nb, 15 * 64 + 32, tid);
        VMW(4);
        BAR();
        MF16(aB, bB, 0);
        RDA(aA, (1 << 2) | 0, 0);
        RDB(bA, (1 << 2) | 2);
        VMW(0);
        BAR();
    }
    {   // t = 15 (p = 1): drain
        MF16(aA, bA, 0);
        RDA(aB, (1 << 2) | 1, 0);
        RDB(bB, (1 << 2) | 3);
        MF16(aB, bB, 0);
    }

    // epilogue: packed VT store (accumulation order unchanged)
#pragma unroll
    for (int j = 0; j < 4; ++j) {
        int n_g = nb + wn + j * 16 + lr;
        float bias = bc[n_g];
        int c = n_g & 1023;
#pragma unroll
        for (int i = 0; i < 4; ++i) {
            int m0 = mb + wm + i * 16 + lq * 4;
            int bidx = m0 >> 11, s0 = m0 & 2047;
            u16 pk[4];
#pragma unroll
            for (int r = 0; r < 4; ++r) pk[r] = f2h(acc[i][j][r] + bias);
            size_t idx = ((size_t)(bidx * KC + c)) * S_ + s0;
            if (idx + 3 < VT_ELEMS)
                *(ushort4*)&VT[idx] = make_ushort4(pk[0], pk[1], pk[2], pk[3]);
        }
    }
}

// ---------------- GEMM2 (256^2 windows, zc==4 path): extended-K=3072 ----------------
// z-patch XCD swizzle: xcd = (z, m-half) -> its 32 blocks = 4 m-bands x 8
// n-cols of ONE z. A x1/z, B x2/z. (R20 version — measured best at 98.7-99.9us.)
__global__ __launch_bounds__(512, 2) void k_gemm2_256(
    const u16* __restrict__ Qh, const u16* __restrict__ Ql,
    const u16* __restrict__ Kh, const u16* __restrict__ Kl,
    float* __restrict__ SC, int zbase) {
    __shared__ __attribute__((aligned(16))) u16 lds[8][8192];
    int tid = threadIdx.x;
    int L = blockIdx.z * 64 + blockIdx.y * 8 + blockIdx.x;  // [0,256)
    int xcd = L & 7, slot = L >> 3;            // slot [0,32)
    int zl = xcd >> 1;                         // local z [0,4)
    int wy = ((xcd & 1) << 2) + (slot & 3);    // [0,8)
    int wx = slot >> 2;                        // [0,8)
    int z = zbase + zl;
    const u16* Aq = Qh + (size_t)z * S_ * KC;
    const u16* Al = Ql + (size_t)z * S_ * KC;
    const u16* Bh = Kh + (size_t)z * S_ * KC;
    const u16* Bl = Kl + (size_t)z * S_ * KC;
    int nb = wx * 256, mb = wy * 256;
    const int NT = 48;

    int lane = tid & 63, wave = tid >> 6;
    int wm = (wave >> 2) * 128, wn = (wave & 3) * 64;   // 2x4 waves
    int lr = lane & 15, lq = lane >> 4;
    int lqs8 = (lq ^ (((lr >> 3) & 1) << 1)) * 8;
    int aoffs = (wm + lr) * 32 + lqs8;
    int boffs = (wn + lr) * 32 + lqs8;

    f32x4 acc[8][4] = {};
    half8 aA[4], aB[4], bA[4], bB[4];

    // prologue: tile 0 (seg0) both halves + tile 1 k0
    stage_half(&lds[0][0], Aq, mb, 0, tid);
    stage_half(&lds[2][0], Bh, nb, 0, tid);
    stage_half(&lds[1][0], Aq, mb, 32, tid);
    stage_half(&lds[3][0], Bh, nb, 32, tid);
    stage_half(&lds[4][0], Aq, mb, 64, tid);
    stage_half(&lds[6][0], Bh, nb, 64, tid);
    VMW(8);
    BAR();
    RDB(bA, 2);
    RDA(aA, 0, 0);

    for (int t = 0; t < NT - 2; ++t) {
        const int p = t & 1;
        const int t1 = t + 1, t2 = t + 2;
        const int sg1 = t1 >> 4, sg2 = t2 >> 4;
        const u16* a1 = (sg1 == 1) ? Al : Aq;
        const u16* b1 = (sg1 == 2) ? Bl : Bh;
        const u16* a2 = (sg2 == 1) ? Al : Aq;
        const u16* b2 = (sg2 == 2) ? Bl : Bh;
        const int k1 = ((t1 & 15) << 6) + 32;
        const int k2 = (t2 & 15) << 6;
        W0(p, stage_half(&lds[((p ^ 1) << 2) | 1][0], a1, mb, k1, tid), VMW(6));
        W1(p, stage_half(&lds[((p ^ 1) << 2) | 3][0], b1, nb, k1, tid));
        W2(p, stage_half(&lds[(p << 2) | 0][0], a2, mb, k2, tid), VMW(6));
        W3(p, stage_half(&lds[(p << 2) | 2][0], b2, nb, k2, tid));
    }
    {   // t = 46 (p = 0): stage tile 47 (seg2: Qh, Kl) k1 only
        const int k1 = ((47 & 15) << 6) + 32;
        W0(0, stage_half(&lds[(1 << 2) | 1][0], Aq, mb, k1, tid), VMW(6));
        W1(0, stage_half(&lds[(1 << 2) | 3][0], Bl, nb, k1, tid));
        W2(0, NOP_, VMW(4));
        W3(0, NOP_);
    }
    {   // t = 47 (p = 1): drain
        W0(1, NOP_, VMW(0));
        W1(1, NOP_);
        W2(1, NOP_, NOP_);
        W3L();
    }

    // epilogue: SC[zl][m][n] fp32
    size_t sc_limit = (size_t)gridDim.z * S_ * S_;
#pragma unroll
    for (int j = 0; j < 4; ++j) {
        int n_g = nb + wn + j * 16 + lr;
#pragma unroll
        for (int i = 0; i < 8; ++i) {
            int m0 = mb + wm + i * 16 + lq * 4;
#pragma unroll
            for (int r = 0; r < 4; ++r) {
                size_t idx = ((size_t)zl * S_ + m0 + r) * S_ + n_g;
                if (idx < sc_limit) SC[idx] = acc[i][j][r];
            }
        }
    }
}

// ---------------- GEMM2 (128^2 windows, zc<4 fallback): extended-K=3072 ----------------
__global__ __launch_bounds__(256, 2) void k_gemm2w(
    const u16* __restrict__ Qh, const u16* __restrict__ Ql,
    const u16* __restrict__ Kh, const u16* __restrict__ Kl,
    float* __restrict__ SC, int zbase) {
    __shared__ __attribute__((aligned(16))) u16 lds[8][4096];
    int tid = threadIdx.x;
    int z = zbase + blockIdx.z;
    const u16* Aq  = Qh + (size_t)z * S_ * KC;
    const u16* Alo = Ql + (size_t)z * S_ * KC;
    const u16* Bh  = Kh + (size_t)z * S_ * KC;
    const u16* Blo = Kl + (size_t)z * S_ * KC;
    int nb = blockIdx.x * 128, mb = blockIdx.y * 128;

    int lane = tid & 63, wave = tid >> 6;
    int wm = (wave >> 1) * 64, wn = (wave & 1) * 64;    // 2x2 waves
    int lr = lane & 15, lq = lane >> 4;
    int lqs8 = (lq ^ (((lr >> 3) & 1) << 1)) * 8;
    int aoffs = (wm + lr) * 32 + lqs8;
    int boffs = (wn + lr) * 32 + lqs8;

    f32x4 acc[4][4] = {};
    half8 aA[4], aB[4], bA[4], bB[4];

    stage_half8(&lds[0][0], Aq, KC, mb, 0, tid);
    stage_half8(&lds[2][0], Bh, KC, nb, 0, tid);
    stage_half8(&lds[1][0], Aq, KC, mb, 32, tid);
    stage_half8(&lds[3][0], Bh, KC, nb, 32, tid);
    stage_half8(&lds[4][0], Aq, KC, mb, 64, tid);
    stage_half8(&lds[6][0], Bh, KC, nb, 64, tid);
    VMW(4);
    BAR();
    RDA(aA, 0, 0);
    RDB(bA, 2);

    for (int t = 0; t < 46; ++t) {
        const int p = t & 1;
        const int t1 = t + 1, t2 = t + 2;
        const u16* a1 = ((t1 >> 4) == 1) ? Alo : Aq;
        const u16* b1 = ((t1 >> 4) == 2) ? Blo : Bh;
        const u16* a2 = ((t2 >> 4) == 1) ? Alo : Aq;
        const u16* b2 = ((t2 >> 4) == 2) ? Blo : Bh;
        const int k1 = ((t1 & 15) << 6) + 32;
        const int k2 = (t2 & 15) << 6;
        MF16(aA, bA, 0);
        RDA(aB, (p << 2) | 1, 0);
        RDB(bB, (p << 2) | 3);
        stage_half8(&lds[((p ^ 1) << 2) | 1][0], a1, KC, mb, k1, tid);
        stage_half8(&lds[((p ^ 1) << 2) | 3][0], b1, KC, nb, k1, tid);
        VMW(4);
        BAR();
        MF16(aB, bB, 0);
        RDA(aA, ((p ^ 1) << 2) | 0, 0);
        RDB(bA, ((p ^ 1) << 2) | 2);
        stage_half8(&lds[(p << 2) | 0][0], a2, KC, mb, k2, tid);
        stage_half8(&lds[(p << 2) | 2][0], b2, KC, nb, k2, tid);
        VMW(4);
        BAR();
    }
    {   // t = 46 (p = 0)
        MF16(aA, bA, 0);
        RDA(aB, 1, 0);
        RDB(bB, 3);
        stage_half8(&lds[(1 << 2) | 1][0], Aq, KC, mb, ((47 & 15) << 6) + 32, tid);
        stage_half8(&lds[(1 << 2) | 3][0], Blo, KC, nb, ((47 & 15) << 6) + 32, tid);
        VMW(4);
        BAR();
        MF16(aB, bB, 0);
        RDA(aA, (1 << 2) | 0, 0);
        RDB(bA, (1 << 2) | 2);
        VMW(0);
        BAR();
    }
    {   // t = 47 (p = 1): drain
        MF16(aA, bA, 0);
        RDA(aB, (1 << 2) | 1, 0);
        RDB(bB, (1 << 2) | 3);
        MF16(aB, bB, 0);
    }

    size_t sc_limit = (size_t)gridDim.z * S_ * S_;
#pragma unroll
    for (int j = 0; j < 4; ++j) {
        int n_g = nb + wn + j * 16 + lr;
#pragma unroll
        for (int i = 0; i < 4; ++i) {
            int m0 = mb + wm + i * 16 + lq * 4;
#pragma unroll
            for (int r = 0; r < 4; ++r) {
                size_t idx = ((size_t)blockIdx.z * S_ + m0 + r) * S_ + n_g;
                if (idx < sc_limit) SC[idx] = acc[i][j][r];
            }
        }
    }
}

// ---------------- softmax: SC fp32 -> AT fp16 (vectorized I/O) ----------------
__global__ __launch_bounds__(256) void k_softmax(const float* __restrict__ SC,
                                                 u16* __restrict__ AT, int zbase) {
    int row = blockIdx.x;
    const float* src = SC + (size_t)row * S_;
    size_t drow = (size_t)zbase * S_ + row;
    u16* dst = AT + drow * S_;
    int tid = threadIdx.x;
    float4 va = *(const float4*)(src + tid * 8);
    float4 vb = *(const float4*)(src + tid * 8 + 4);
    float v[8] = {va.x, va.y, va.z, va.w, vb.x, vb.y, vb.z, vb.w};
    float m = v[0];
#pragma unroll
    for (int i = 1; i < 8; ++i) m = fmaxf(m, v[i]);
    for (int off = 32; off > 0; off >>= 1) m = fmaxf(m, __shfl_down(m, off));
    __shared__ float redm[4], reds[4];
    if ((tid & 63) == 0) redm[tid >> 6] = m;
    __syncthreads();
    m = fmaxf(fmaxf(redm[0], redm[1]), fmaxf(redm[2], redm[3]));
    float s = 0.f;
#pragma unroll
    for (int i = 0; i < 8; ++i) { v[i] = __expf(v[i] - m); s += v[i]; }
    for (int off = 32; off > 0; off >>= 1) s += __shfl_down(s, off);
    if ((tid & 63) == 0) reds[tid >> 6] = s;
    __syncthreads();
    float inv = 1.0f / (reds[0] + reds[1] + reds[2] + reds[3]);
    if (drow * S_ + 2047 < AT_ELEMS) {
        u16 pk[8];
#pragma unroll
        for (int i = 0; i < 8; ++i) pk[i] = f2h(v[i] * inv);
        uint4 o;
        o.x = (unsigned)pk[0] | ((unsigned)pk[1] << 16);
        o.y = (unsigned)pk[2] | ((unsigned)pk[3] << 16);
        o.z = (unsigned)pk[4] | ((unsigned)pk[5] << 16);
        o.w = (unsigned)pk[6] | ((unsigned)pk[7] << 16);
        *(uint4*)(dst + tid * 8) = o;
    }
}

// ---------------- GEMM3 (128^2 windows): out = attn @ Vcat, NT=32 ----------------
__global__ __launch_bounds__(256, 2) void k_gemm3w(
    const u16* __restrict__ AT, const u16* __restrict__ VT,
    float* __restrict__ out, int out_size, int full) {
    __shared__ __attribute__((aligned(16))) u16 lds[8][4096];
    int tid = threadIdx.x;
    int L = blockIdx.z * 128 + blockIdx.y * 8 + blockIdx.x;  // [0,512)
    int xcd = L & 7, slot = L >> 3;            // slot [0,64)
    int z = xcd >> 1;                          // [0,4)
    int wy = ((xcd & 1) << 3) + (slot & 7);    // [0,16)
    int wx = slot >> 3;                        // [0,8)
    const u16* Abase = AT + (size_t)z * S_ * S_;   // [S][S], ld=S
    const u16* Bbase = VT + (size_t)z * KC * S_;   // [KC][S], ld=S (B^T form)
    int nb = wx * 128, mb = wy * 128;

    int lane = tid & 63, wave = tid >> 6;
    int wm = (wave >> 1) * 64, wn = (wave & 1) * 64;    // 2x2 waves
    int lr = lane & 15, lq = lane >> 4;
    int lqs8 = (lq ^ (((lr >> 3) & 1) << 1)) * 8;
    int aoffs = (wm + lr) * 32 + lqs8;
    int boffs = (wn + lr) * 32 + lqs8;

    f32x4 acc[4][4] = {};
    half8 aA[4], aB[4], bA[4], bB[4];

    // prologue: tile 0 both halves + tile 1 k0
    stage_half8(&lds[0][0], Abase, S_, mb, 0, tid);
    stage_half8(&lds[2][0], Bbase, S_, nb, 0, tid);
    stage_half8(&lds[1][0], Abase, S_, mb, 32, tid);
    stage_half8(&lds[3][0], Bbase, S_, nb, 32, tid);
    stage_half8(&lds[4][0], Abase, S_, mb, 64, tid);
    stage_half8(&lds[6][0], Bbase, S_, nb, 64, tid);
    VMW(4);
    BAR();
    RDA(aA, 0, 0);
    RDB(bA, 2);

    for (int t = 0; t < 30; ++t) {
        const int p = t & 1;
        const int k1 = (t + 1) * 64 + 32;
        const int k2 = (t + 2) * 64;
        MF16(aA, bA, 0);
        RDA(aB, (p << 2) | 1, 0);
        RDB(bB, (p << 2) | 3);
        stage_half8(&lds[((p ^ 1) << 2) | 1][0], Abase, S_, mb, k1, tid);
        stage_half8(&lds[((p ^ 1) << 2) | 3][0], Bbase, S_, nb, k1, tid);
        VMW(4);
        BAR();
        MF16(aB, bB, 0);
        RDA(aA, ((p ^ 1) << 2) | 0, 0);
        RDB(bA, ((p ^ 1) << 2) | 2);
        stage_half8(&lds[(p << 2) | 0][0], Abase, S_, mb, k2, tid);
        stage_half8(&lds[(p << 2) | 2][0], Bbase, S_, nb, k2, tid);
        VMW(4);
        BAR();
    }
    {   // t = 30 (p = 0): stage tile 31 k1 only
        MF16(aA, bA, 0);
        RDA(aB, 1, 0);
        RDB(bB, 3);
        stage_half8(&lds[(1 << 2) | 1][0], Abase, S_, mb, 31 * 64 + 32, tid);
        stage_half8(&lds[(1 << 2) | 3][0], Bbase, S_, nb, 31 * 64 + 32, tid);
        VMW(4);
        BAR();
        MF16(aB, bB, 0);
        RDA(aA, (1 << 2) | 0, 0);
        RDB(bA, (1 << 2) | 2);
        VMW(0);
        BAR();
    }
    {   // t = 31 (p = 1): drain
        MF16(aA, bA, 0);
        RDA(aB, (1 << 2) | 1, 0);
        RDB(bB, (1 << 2) | 3);
        MF16(aB, bB, 0);
    }

    // planar epilogue
#pragma unroll
    for (int j = 0; j < 4; ++j) {
        int f = nb + wn + j * 16 + lr;
#pragma unroll
        for (int i = 0; i < 4; ++i) {
            int s0 = mb + wm + i * 16 + lq * 4;
#pragma unroll
            for (int r = 0; r < 4; ++r) {
                size_t base = ((size_t)z * S_ + s0 + r) * D_;
                if (f < D_) {
                    size_t o = base + f;
                    if (o < (size_t)out_size) out[o] = acc[i][j][r];
                } else if (full) {
                    size_t o = (size_t)RE_PLANE + base + (f - D_);
                    if (o < (size_t)out_size) out[o] = acc[i][j][r];
                }
            }
        }
    }
}

// ---------------- launch ----------------

extern "C" void kernel_launch(void* const* d_in, const int* in_sizes, int n_in,
                              void* d_out, int out_size, void* d_ws, size_t ws_size,
                              hipStream_t stream) {
    (void)in_sizes; (void)n_in;
    const float* xr  = (const float*)d_in[0];
    const float* xi  = (const float*)d_in[1];
    const float* Wqr = (const float*)d_in[2];
    const float* Wqi = (const float*)d_in[3];
    const float* bqr = (const float*)d_in[4];
    const float* bqi = (const float*)d_in[5];
    const float* Wkr = (const float*)d_in[6];
    const float* Wki = (const float*)d_in[7];
    const float* bkr = (const float*)d_in[8];
    const float* bki = (const float*)d_in[9];
    const float* Wvr = (const float*)d_in[10];
    const float* Wvi = (const float*)d_in[11];
    const float* bvr = (const float*)d_in[12];
    const float* bvi = (const float*)d_in[13];
    float* out = (float*)d_out;

    constexpr size_t SZ_X  = X_ELEMS * 2;          // 16 MiB each (Xh, Xl)
    constexpr size_t SZ_W  = W_ELEMS * 2;          // 6 MiB
    constexpr size_t SZ_BC = (size_t)N1 * 4;
    constexpr size_t SZ_QK = QK_ELEMS * 2;         // 16 MiB each (Qh,Ql,Kh,Kl)
    constexpr size_t SZ_VT = VT_ELEMS * 2;         // 16 MiB
    constexpr size_t SZ_SC_B = (size_t)S_ * S_ * 4;  // 16 MiB per batch

    char* p = (char*)d_ws;
    size_t off = 0;
    auto take = [&](size_t sz) {
        char* r = p + off;
        off += (sz + 255) & ~(size_t)255;
        return r;
    };
    u16*   Xh = (u16*)take(SZ_X);
    u16*   Xl = (u16*)take(SZ_X);
    u16*   Wh = (u16*)take(SZ_W);
    float* bc = (float*)take(SZ_BC);
    u16*   Qh = (u16*)take(SZ_QK);
    u16*   Ql = (u16*)take(SZ_QK);
    u16*   Kh = (u16*)take(SZ_QK);
    u16*   Kl = (u16*)take(SZ_QK);
    u16*   VT = (u16*)take(SZ_VT);
    u16*   AT = Xh;  // aliases Xh+Xl (32 MiB, dead after gemm1 kernels)
    float* SC = (float*)(p + off);

    int nz = 0;
    if (ws_size > off) nz = (int)((ws_size - off) / SZ_SC_B);
    if (nz > B_) nz = B_;
    if (nz < 1) {
        k_diag<<<16, 256, 0, stream>>>(out, out_size, 1000.0f + (float)(ws_size >> 20));
        return;
    }

    int full = (out_size >= 2 * RE_PLANE) ? 1 : 0;

    k_prep<<<4096 + 12288 + 12, 256, 0, stream>>>(
        xr, xi, Wqr, Wqi, Wkr, Wki, Wvr, Wvi,
        bqr, bqi, bkr, bki, bvr, bvi, Xh, Xl, Wh, bc);
    k_gemm1qk<<<dim3(8, 32), 512, 0, stream>>>(Xh, Xl, Wh, bc, Qh, Ql, Kh, Kl);
    k_gemm1v<<<dim3(8, 64), 256, 0, stream>>>(Xh, Wh, bc, VT);

    for (int z0 = 0; z0 < B_; z0 += nz) {
        int zc = (B_ - z0 < nz) ? (B_ - z0) : nz;
        if (zc == B_) {
            k_gemm2_256<<<dim3(8, 8, 4), 512, 0, stream>>>(
                Qh, Ql, Kh, Kl, SC, z0);
        } else {
            k_gemm2w<<<dim3(S_ / 128, S_ / 128, zc), 256, 0, stream>>>(
                Qh, Ql, Kh, Kl, SC, z0);
        }
        k_softmax<<<zc * S_, 256, 0, stream>>>(SC, AT, z0);
    }
    k_gemm3w<<<dim3(KC / 128, S_ / 128, B_), 256, 0, stream>>>(AT, VT, out, out_size, full);
}